// Round 5
// baseline (129.304 us; speedup 1.0000x reference)
//
#include <hip/hip_runtime.h>

typedef float fx4 __attribute__((ext_vector_type(4)));

// Fast 8-point DCT-II on a strided register slice (stride S compile-time).
// o[u] = sum_x a[x]*cos((2x+1)u*pi/16), in place.
template <int S>
__device__ __forceinline__ void dct8s(float* m) {
    const float a0 = m[0*S], a1 = m[1*S], a2 = m[2*S], a3 = m[3*S];
    const float a4 = m[4*S], a5 = m[5*S], a6 = m[6*S], a7 = m[7*S];
    const float s0 = a0 + a7, s1 = a1 + a6, s2 = a2 + a5, s3 = a3 + a4;
    const float d0 = a0 - a7, d1 = a1 - a6, d2 = a2 - a5, d3 = a3 - a4;
    const float ss0 = s0 + s3, ss1 = s1 + s2;
    const float ds0 = s0 - s3, ds1 = s1 - s2;
    m[0*S] = ss0 + ss1;
    m[4*S] = 0.70710678f * (ss0 - ss1);
    m[2*S] = fmaf(0.92387953f, ds0,  0.38268343f * ds1);
    m[6*S] = fmaf(0.38268343f, ds0, -0.92387953f * ds1);
    m[1*S] = fmaf(0.98078528f, d0, fmaf( 0.83146961f, d1, fmaf( 0.55557023f, d2,  0.19509032f * d3)));
    m[3*S] = fmaf(0.83146961f, d0, fmaf(-0.19509032f, d1, fmaf(-0.98078528f, d2, -0.55557023f * d3)));
    m[5*S] = fmaf(0.55557023f, d0, fmaf(-0.98078528f, d1, fmaf( 0.19509032f, d2,  0.83146961f * d3)));
    m[7*S] = fmaf(0.19509032f, d0, fmaf(-0.55557023f, d1, fmaf( 0.83146961f, d2, -0.98078528f * d3)));
}

// One thread per 8x8 block, fully in-register, zero cross-lane / zero LDS:
//   16x dwordx4 load -> 8 row-DCTs -> 8 col-DCTs (transpose = reg indexing)
//   -> single DC correction + scale -> 16x dwordx4 store.
// All loop indices compile-time after full unroll; deep independent ILP per
// thread hides memory latency (the R1-R4 kernels were latency-bound).
__global__ __launch_bounds__(256) void dct8x8_kernel(const float* __restrict__ in,
                                                     float* __restrict__ out) {
    const size_t t = (size_t)blockIdx.x * 256 + threadIdx.x;
    const fx4* p = reinterpret_cast<const fx4*>(in) + t * 16;

    float m[64];
    // ---- 16 independent vector loads (256 B, 4 full cache lines) ----
#pragma unroll
    for (int i = 0; i < 16; ++i) {
        fx4 v = p[i];
        m[i * 4 + 0] = v[0];
        m[i * 4 + 1] = v[1];
        m[i * 4 + 2] = v[2];
        m[i * 4 + 3] = v[3];
    }

    // ---- 8 independent row DCTs (stride 1) ----
#pragma unroll
    for (int r = 0; r < 8; ++r) dct8s<1>(&m[r * 8]);

    // ---- 8 independent column DCTs (stride 8; transpose is just indexing) ----
#pragma unroll
    for (int c = 0; c < 8; ++c) dct8s<8>(&m[c]);

    // ---- -128 input shift touches only (0,0): -128*64 before scale ----
    m[0] -= 8192.0f;

    // ---- scale[u][v] = (0.5*alpha_u)(0.5*alpha_v), all compile-time ----
#pragma unroll
    for (int u = 0; u < 8; ++u) {
        const float su = (u == 0) ? 0.35355339059f : 0.5f;
#pragma unroll
        for (int v = 0; v < 8; ++v) {
            const float sv = (v == 0) ? 0.35355339059f : 0.5f;
            m[u * 8 + v] *= su * sv;
        }
    }

    // ---- 16 independent vector stores ----
    fx4* q = reinterpret_cast<fx4*>(out) + t * 16;
#pragma unroll
    for (int i = 0; i < 16; ++i) {
        fx4 v = { m[i * 4 + 0], m[i * 4 + 1], m[i * 4 + 2], m[i * 4 + 3] };
        q[i] = v;
    }
}

extern "C" void kernel_launch(void* const* d_in, const int* in_sizes, int n_in,
                              void* d_out, int out_size, void* d_ws, size_t ws_size,
                              hipStream_t stream) {
    const float* in = (const float*)d_in[0];
    float* out = (float*)d_out;
    const int n = in_sizes[0];          // 64*3*4096*64 = 50,331,648 floats
    const int nblocks = n / 64;         // 786,432 8x8 blocks, one thread each
    const int grid = nblocks / 256;     // divides exactly
    hipLaunchKernelGGL(dct8x8_kernel, dim3(grid), dim3(256), 0, stream,
                       in, out);
}

// Round 6
// 76.400 us; speedup vs baseline: 1.6925x; 1.6925x over previous
//
#include <hip/hip_runtime.h>

typedef float fx4 __attribute__((ext_vector_type(4)));

// Fast 8-point DCT-II (unnormalized: o[u] = sum_x a[x]*cos((2x+1)u*pi/16)),
// even/odd factored. All coefficients literal.
__device__ __forceinline__ void dct8(const float a[8], float o[8]) {
    const float s0 = a[0] + a[7], s1 = a[1] + a[6], s2 = a[2] + a[5], s3 = a[3] + a[4];
    const float d0 = a[0] - a[7], d1 = a[1] - a[6], d2 = a[2] - a[5], d3 = a[3] - a[4];
    const float ss0 = s0 + s3, ss1 = s1 + s2;
    const float ds0 = s0 - s3, ds1 = s1 - s2;
    o[0] = ss0 + ss1;
    o[4] = 0.70710678f * (ss0 - ss1);
    o[2] = fmaf(0.92387953f, ds0,  0.38268343f * ds1);
    o[6] = fmaf(0.38268343f, ds0, -0.92387953f * ds1);
    o[1] = fmaf(0.98078528f, d0, fmaf( 0.83146961f, d1, fmaf( 0.55557023f, d2,  0.19509032f * d3)));
    o[3] = fmaf(0.83146961f, d0, fmaf(-0.19509032f, d1, fmaf(-0.98078528f, d2, -0.55557023f * d3)));
    o[5] = fmaf(0.55557023f, d0, fmaf(-0.98078528f, d1, fmaf( 0.19509032f, d2,  0.83146961f * d3)));
    o[7] = fmaf(0.19509032f, d0, fmaf(-0.55557023f, d1, fmaf( 0.83146961f, d2, -0.98078528f * d3)));
}

// 8 lanes per 8x8 block, lane l owns row l end-to-end. Two LDS transposes,
// all exchange within the wave's own 8-lane groups -> NO barriers.
// LDS layout per group (stride 68 words so 4*G mod 32 is distinct per group):
//   M[row][v] at word  base + (v&4)*8 + row*4 + (v&3)
// -> write own row = 2x ds_write_b128, lane-consecutive 16B (uniform banks)
// -> read column l = 8x ds_read_b32, exactly 2 lanes/bank (free)
__global__ __launch_bounds__(256) void dct8x8_kernel(const float* __restrict__ in,
                                                     float* __restrict__ out) {
    __shared__ alignas(16) float lds1[32 * 68];
    __shared__ alignas(16) float lds2[32 * 68];

    const int tid  = blockIdx.x * 256 + threadIdx.x;   // grid divides exactly
    const int l    = threadIdx.x & 7;
    const int base = (threadIdx.x >> 3) * 68;          // per-group region
    const int cbase = base + (l & 4) * 8 + (l & 3);    // column-access base

    // ---- load row l of the block (32 B, fully coalesced) ----
    const fx4* p = reinterpret_cast<const fx4*>(in) + (size_t)tid * 2;
    fx4 v0 = p[0];
    fx4 v1 = p[1];
    float a[8] = { v0[0], v0[1], v0[2], v0[3], v1[0], v1[1], v1[2], v1[3] };

    // ---- row pass ----
    float r[8];
    dct8(a, r);
    r[0] -= 1024.0f;   // global -128 shift only affects the row DC (8*128)

    // ---- transpose #1: write row (2x b128), read column l (8x b32) ----
    fx4 w0 = { r[0], r[1], r[2], r[3] };
    fx4 w1 = { r[4], r[5], r[6], r[7] };
    *reinterpret_cast<fx4*>(&lds1[base + l * 4])      = w0;
    *reinterpret_cast<fx4*>(&lds1[base + 32 + l * 4]) = w1;

    float t[8];
#pragma unroll
    for (int y = 0; y < 8; ++y) t[y] = lds1[cbase + y * 4];

    // ---- column pass -> output column l ----
    float o[8];
    dct8(t, o);

    // ---- scale[u][l] = (0.5*alpha_u)(0.5*alpha_l) ----
    const float sl = (l == 0) ? 0.35355339059f : 0.5f;
#pragma unroll
    for (int u = 0; u < 8; ++u) o[u] *= sl * ((u == 0) ? 0.35355339059f : 0.5f);

    // ---- transpose #2: scatter column (8x b32), read row l (2x b128) ----
#pragma unroll
    for (int u = 0; u < 8; ++u) lds2[cbase + u * 4] = o[u];

    fx4 q0 = *reinterpret_cast<const fx4*>(&lds2[base + l * 4]);
    fx4 q1 = *reinterpret_cast<const fx4*>(&lds2[base + 32 + l * 4]);

    // ---- coalesced regular store ----
    fx4* qp = reinterpret_cast<fx4*>(out) + (size_t)tid * 2;
    qp[0] = q0;
    qp[1] = q1;
}

extern "C" void kernel_launch(void* const* d_in, const int* in_sizes, int n_in,
                              void* d_out, int out_size, void* d_ws, size_t ws_size,
                              hipStream_t stream) {
    const float* in = (const float*)d_in[0];
    float* out = (float*)d_out;
    const int n = in_sizes[0];          // 64*3*4096*64 = 50,331,648 floats
    const int nthreads = n / 8;         // one lane per block-row
    const int grid = (nthreads + 255) / 256;
    hipLaunchKernelGGL(dct8x8_kernel, dim3(grid), dim3(256), 0, stream,
                       in, out);
}

// Round 7
// 75.773 us; speedup vs baseline: 1.7065x; 1.0083x over previous
//
#include <hip/hip_runtime.h>

typedef float fx4 __attribute__((ext_vector_type(4)));

// Fast 8-point DCT-II (unnormalized: o[u] = sum_x a[x]*cos((2x+1)u*pi/16)),
// even/odd factored. All coefficients literal.
__device__ __forceinline__ void dct8(const float a[8], float o[8]) {
    const float s0 = a[0] + a[7], s1 = a[1] + a[6], s2 = a[2] + a[5], s3 = a[3] + a[4];
    const float d0 = a[0] - a[7], d1 = a[1] - a[6], d2 = a[2] - a[5], d3 = a[3] - a[4];
    const float ss0 = s0 + s3, ss1 = s1 + s2;
    const float ds0 = s0 - s3, ds1 = s1 - s2;
    o[0] = ss0 + ss1;
    o[4] = 0.70710678f * (ss0 - ss1);
    o[2] = fmaf(0.92387953f, ds0,  0.38268343f * ds1);
    o[6] = fmaf(0.38268343f, ds0, -0.92387953f * ds1);
    o[1] = fmaf(0.98078528f, d0, fmaf( 0.83146961f, d1, fmaf( 0.55557023f, d2,  0.19509032f * d3)));
    o[3] = fmaf(0.83146961f, d0, fmaf(-0.19509032f, d1, fmaf(-0.98078528f, d2, -0.55557023f * d3)));
    o[5] = fmaf(0.55557023f, d0, fmaf(-0.98078528f, d1, fmaf( 0.19509032f, d2,  0.83146961f * d3)));
    o[7] = fmaf(0.19509032f, d0, fmaf(-0.55557023f, d1, fmaf( 0.83146961f, d2, -0.98078528f * d3)));
}

// 8 lanes per 8x8 block, lane l owns row l end-to-end. Two LDS transposes in
// ONE shared buffer (same-wave DS ordering makes the reuse safe; all exchange
// is within the wave's own 8-lane groups -> NO barriers).
// Cache policy: NONTEMPORAL loads (input = evict-first, doesn't displace the
// output in L3) + regular stores (output L3-resident across graph replays ->
// steady-state HBM traffic ~reads only).
__global__ __launch_bounds__(256) void dct8x8_kernel(const float* __restrict__ in,
                                                     float* __restrict__ out) {
    __shared__ alignas(16) float lds1[32 * 68];   // 8.7 KB -> high occupancy

    const int tid  = blockIdx.x * 256 + threadIdx.x;   // grid divides exactly
    const int l    = threadIdx.x & 7;
    const int base = (threadIdx.x >> 3) * 68;          // per-group region
    const int cbase = base + (l & 4) * 8 + (l & 3);    // column-access base

    // ---- nontemporal load of row l (32 B, fully coalesced, evict-first) ----
    const fx4* p = reinterpret_cast<const fx4*>(in) + (size_t)tid * 2;
    fx4 v0 = __builtin_nontemporal_load(p);
    fx4 v1 = __builtin_nontemporal_load(p + 1);
    float a[8] = { v0[0], v0[1], v0[2], v0[3], v1[0], v1[1], v1[2], v1[3] };

    // ---- row pass ----
    float r[8];
    dct8(a, r);
    r[0] -= 1024.0f;   // global -128 shift only affects the row DC (8*128)

    // ---- transpose #1: write row (2x b128), read column l (8x b32) ----
    fx4 w0 = { r[0], r[1], r[2], r[3] };
    fx4 w1 = { r[4], r[5], r[6], r[7] };
    *reinterpret_cast<fx4*>(&lds1[base + l * 4])      = w0;
    *reinterpret_cast<fx4*>(&lds1[base + 32 + l * 4]) = w1;

    float t[8];
#pragma unroll
    for (int y = 0; y < 8; ++y) t[y] = lds1[cbase + y * 4];

    // ---- column pass -> output column l ----
    float o[8];
    dct8(t, o);

    // ---- scale[u][l] = (0.5*alpha_u)(0.5*alpha_l) ----
    const float sl = (l == 0) ? 0.35355339059f : 0.5f;
#pragma unroll
    for (int u = 0; u < 8; ++u) o[u] *= sl * ((u == 0) ? 0.35355339059f : 0.5f);

    // ---- transpose #2 (same buffer): scatter column (8x b32), read row (2x b128) ----
#pragma unroll
    for (int u = 0; u < 8; ++u) lds1[cbase + u * 4] = o[u];

    fx4 q0 = *reinterpret_cast<const fx4*>(&lds1[base + l * 4]);
    fx4 q1 = *reinterpret_cast<const fx4*>(&lds1[base + 32 + l * 4]);

    // ---- coalesced REGULAR store (L3-allocating; stays resident for replays) ----
    fx4* qp = reinterpret_cast<fx4*>(out) + (size_t)tid * 2;
    qp[0] = q0;
    qp[1] = q1;
}

extern "C" void kernel_launch(void* const* d_in, const int* in_sizes, int n_in,
                              void* d_out, int out_size, void* d_ws, size_t ws_size,
                              hipStream_t stream) {
    const float* in = (const float*)d_in[0];
    float* out = (float*)d_out;
    const int n = in_sizes[0];          // 64*3*4096*64 = 50,331,648 floats
    const int nthreads = n / 8;         // one lane per block-row
    const int grid = (nthreads + 255) / 256;
    hipLaunchKernelGGL(dct8x8_kernel, dim3(grid), dim3(256), 0, stream,
                       in, out);
}